// Round 2
// baseline (163.043 us; speedup 1.0000x reference)
//
#include <hip/hip_runtime.h>
#include <hip/hip_bf16.h>

#define BN 8192      // batch rows
#define MM 8199      // real rows (BN + 7 centers)
#define MP 8208      // padded to multiple of 16
#define HH 128       // feature dim
#define EE 256       // center embedding dim
#define NTILE 513    // MP / 16 j-tiles
#define JCH 32       // j-chunks (grid.y)
#define K2 10.30496147f   // (0.5/0.07) * log2(e)

typedef __attribute__((ext_vector_type(8))) short short8;   // 8 bf16 = 4 VGPRs
typedef __attribute__((ext_vector_type(4))) float floatx4;

// ---- kernel B (fused A): rn[r] = bf16(row / max(||row||,1e-8)); rows >= BN are
// projected centers computed inline; pad rows [MM,MP) are exact zeros.
__global__ __launch_bounds__(256)
void norm_kernel(const float* __restrict__ reps,
                 const float* __restrict__ centers,
                 const float* __restrict__ fc_w,
                 const float* __restrict__ fc_b,
                 const int* __restrict__ labels,
                 __hip_bfloat16* __restrict__ rn,
                 int* __restrict__ labp) {
  const int lane = threadIdx.x & 63;
  const int r = blockIdx.x * 4 + (threadIdx.x >> 6);
  float2 v = make_float2(0.f, 0.f);
  if (r < BN) {
    v = ((const float2*)(reps + (size_t)r * HH))[lane];
  } else if (r < MM) {
    // curr_centers[c][h] = sum_e centers[c][e]*fc_w[h][e] + fc_b[h]; h = 2*lane, 2*lane+1
    int c = r - BN;
    const float4* ce = (const float4*)(centers + c * EE);
    const float4* w0 = (const float4*)(fc_w + (size_t)(2 * lane) * EE);
    const float4* w1 = (const float4*)(fc_w + (size_t)(2 * lane + 1) * EE);
    float s0 = 0.f, s1 = 0.f;
#pragma unroll 8
    for (int e = 0; e < 64; ++e) {
      float4 a = ce[e];
      float4 x = w0[e];
      float4 y = w1[e];
      s0 += a.x * x.x + a.y * x.y + a.z * x.z + a.w * x.w;
      s1 += a.x * y.x + a.y * y.y + a.z * y.z + a.w * y.w;
    }
    float2 bb = ((const float2*)fc_b)[lane];
    v.x = s0 + bb.x;
    v.y = s1 + bb.y;
  }
  float ss = v.x * v.x + v.y * v.y;
#pragma unroll
  for (int m = 1; m < 64; m <<= 1) ss += __shfl_xor(ss, m);
  float inv = 1.0f / fmaxf(sqrtf(ss), 1e-8f);
  __hip_bfloat162 h2;
  h2.x = __float2bfloat16(v.x * inv);
  h2.y = __float2bfloat16(v.y * inv);
  ((__hip_bfloat162*)(rn + (size_t)r * HH))[lane] = h2;
  if (lane == 0) labp[r] = (r < BN) ? labels[r] : (r < MM ? r - BN : -1);
}

// ---- kernel C: tot_i = sum_{j!=i} e_ij, pos_i = sum over label matches.
// e_ij = exp2((cos_ij - 1) * K2); global-max shift cancels in pos/(pos+neg).
// Pad rows are zero vectors -> constant 9*2^-K2 added to tot, removed in loss_kernel.
__global__ __launch_bounds__(256, 4)
void main_kernel(const __hip_bfloat16* __restrict__ rn,
                 const int* __restrict__ labp,
                 float* __restrict__ tot,
                 float* __restrict__ pos) {
  const int tid = threadIdx.x;
  const int lane = tid & 63;
  const int wv = tid >> 6;
  const int q = lane >> 4, col = lane & 15;
  const int ibase = blockIdx.x * 128 + wv * 32;   // 32 i-rows per wave
  const short* rns = (const short*)rn;

  // A fragments: lane holds A[m=col][k = kk*32 + q*8 + 0..7]
  short8 afrag[2][4];
#pragma unroll
  for (int it = 0; it < 2; ++it) {
    const short8* p = (const short8*)(rns + (size_t)(ibase + it * 16 + col) * HH + q * 8);
    afrag[it][0] = p[0];
    afrag[it][1] = p[4];
    afrag[it][2] = p[8];
    afrag[it][3] = p[12];
  }
  int labi[2][4];
#pragma unroll
  for (int it = 0; it < 2; ++it)
#pragma unroll
    for (int r = 0; r < 4; ++r)
      labi[it][r] = labp[ibase + it * 16 + q * 4 + r];

  float stot[2][4] = {};
  float spos[2][4] = {};

  int t = blockIdx.y;
  // prefetch tile t into (b0..b3, labj)
  const short8* bp = (const short8*)(rns + (size_t)(t * 16 + col) * HH + q * 8);
  short8 b0 = bp[0], b1 = bp[4], b2 = bp[8], b3 = bp[12];
  int labj = labp[t * 16 + col];

  while (t < NTILE) {
    const int tn = t + JCH;
    const int ts = (tn < NTILE) ? tn : t;          // clamp: redundant reload on last iter
    const short8* np = (const short8*)(rns + (size_t)(ts * 16 + col) * HH + q * 8);
    short8 n0 = np[0], n1 = np[4], n2 = np[8], n3 = np[12];
    int labn = labp[ts * 16 + col];

    const int jb = t * 16;
#pragma unroll
    for (int it = 0; it < 2; ++it) {
      floatx4 acc = {0.f, 0.f, 0.f, 0.f};
      acc = __builtin_amdgcn_mfma_f32_16x16x32_bf16(afrag[it][0], b0, acc, 0, 0, 0);
      acc = __builtin_amdgcn_mfma_f32_16x16x32_bf16(afrag[it][1], b1, acc, 0, 0, 0);
      acc = __builtin_amdgcn_mfma_f32_16x16x32_bf16(afrag[it][2], b2, acc, 0, 0, 0);
      acc = __builtin_amdgcn_mfma_f32_16x16x32_bf16(afrag[it][3], b3, acc, 0, 0, 0);
      const bool isdiag = (jb == ibase + it * 16);  // wave-uniform
#pragma unroll
      for (int r = 0; r < 4; ++r) {
        // C/D layout: i = ibase+it*16+q*4+r, j = jb+col
        float e = __builtin_amdgcn_exp2f(__builtin_fmaf(acc[r], K2, -K2));
        if (isdiag && (col == q * 4 + r)) e = 0.f;   // exclude diagonal j==i
        stot[it][r] += e;
        spos[it][r] += (labj == labi[it][r]) ? e : 0.f;
      }
    }
    b0 = n0; b1 = n1; b2 = n2; b3 = n3; labj = labn;
    t = tn;
  }

  // reduce across the 16 column-lanes (xor over low 4 lane bits)
#pragma unroll
  for (int it = 0; it < 2; ++it)
#pragma unroll
    for (int r = 0; r < 4; ++r) {
      float tt = stot[it][r], pp = spos[it][r];
#pragma unroll
      for (int m = 1; m <= 8; m <<= 1) {
        tt += __shfl_xor(tt, m);
        pp += __shfl_xor(pp, m);
      }
      if (col == 0) {
        int i = ibase + it * 16 + q * 4 + r;
        atomicAdd(&tot[i], tt);
        atomicAdd(&pos[i], pp);
      }
    }
}

// ---- kernel D: loss = sum(lv * (lv>0.3)) / (sum(lv>0.3) + eps)
__global__ __launch_bounds__(1024)
void loss_kernel(const float* __restrict__ tot,
                 const float* __restrict__ pos,
                 const int* __restrict__ labels,
                 float* __restrict__ out) {
  __shared__ int hist[8];
  __shared__ float s1[1024], s2[1024];
  const int tid = threadIdx.x;
  if (tid < 8) hist[tid] = 0;
  __syncthreads();
  for (int i = tid; i < BN; i += 1024) atomicAdd(&hist[labels[i]], 1);
  __syncthreads();
  const float padc = 9.0f * exp2f(-K2);   // pad-row contribution to tot (exact-zero rows)
  float lsum = 0.f, msum = 0.f;
  for (int i = tid; i < BN; i += 1024) {
    float t = tot[i] - padc, p = pos[i];
    float c = (float)hist[labels[i]];     // = sum(pos_mask*mask) exactly
    float pr = (p / t) / (c + 1e-8f);
    float lv = -logf(pr + 1e-8f);
    if (lv > 0.3f) { lsum += lv; msum += 1.f; }
  }
  s1[tid] = lsum; s2[tid] = msum;
  __syncthreads();
  for (int st = 512; st > 0; st >>= 1) {
    if (tid < st) { s1[tid] += s1[tid + st]; s2[tid] += s2[tid + st]; }
    __syncthreads();
  }
  if (tid == 0) out[0] = s1[0] / (s2[0] + 1e-8f);
}

extern "C" void kernel_launch(void* const* d_in, const int* in_sizes, int n_in,
                              void* d_out, int out_size, void* d_ws, size_t ws_size,
                              hipStream_t stream) {
  const float* reps    = (const float*)d_in[0];  // [8192,128]
  const int*   labels  = (const int*)d_in[1];    // [8192]
  const float* centers = (const float*)d_in[2];  // [7,256]
  const float* fc_w    = (const float*)d_in[3];  // [128,256]
  const float* fc_b    = (const float*)d_in[4];  // [128]
  float* out = (float*)d_out;

  char* ws = (char*)d_ws;
  int* labp = (int*)ws;                                  // 8208*4 = 32832 B
  __hip_bfloat16* rn = (__hip_bfloat16*)(ws + 40960);    // 8208*128*2 = 2101248 B
  float* tot = (float*)(ws + 40960 + 2101248);           // 8192*4
  float* pos = tot + BN;                                 // 8192*4

  hipMemsetAsync(tot, 0, 2 * BN * sizeof(float), stream);
  norm_kernel<<<MP / 4, 256, 0, stream>>>(reps, centers, fc_w, fc_b, labels, rn, labp);
  main_kernel<<<dim3(BN / 128, JCH), 256, 0, stream>>>(rn, labp, tot, pos);
  loss_kernel<<<1, 1024, 0, stream>>>(tot, pos, labels, out);
}

// Round 3
// 146.379 us; speedup vs baseline: 1.1138x; 1.1138x over previous
//
#include <hip/hip_runtime.h>
#include <hip/hip_bf16.h>

#define BN 8192      // batch rows
#define MM 8199      // real rows (BN + 7 centers)
#define MP 8208      // padded to multiple of 16
#define HH 128       // feature dim
#define EE 256       // center embedding dim
#define NTILE 513    // MP / 16 j-tiles
#define JCH 32       // j-chunks (grid.y)
#define K2 10.30496147f   // (0.5/0.07) * log2(e)

typedef __attribute__((ext_vector_type(8))) short short8;   // 8 bf16 = 4 VGPRs
typedef __attribute__((ext_vector_type(4))) float floatx4;

// ---- norm kernel: rn[r] = bf16(row / max(||row||,1e-8)); rows >= BN are projected
// centers computed inline; pad rows [MM,MP) exact zeros. Also stores
// ssq[r] = sum of squares of the bf16-rounded normalized row (for diag removal).
__global__ __launch_bounds__(256)
void norm_kernel(const float* __restrict__ reps,
                 const float* __restrict__ centers,
                 const float* __restrict__ fc_w,
                 const float* __restrict__ fc_b,
                 const int* __restrict__ labels,
                 __hip_bfloat16* __restrict__ rn,
                 int* __restrict__ labp,
                 float* __restrict__ ssq) {
  const int lane = threadIdx.x & 63;
  const int r = blockIdx.x * 4 + (threadIdx.x >> 6);
  float2 v = make_float2(0.f, 0.f);
  if (r < BN) {
    v = ((const float2*)(reps + (size_t)r * HH))[lane];
  } else if (r < MM) {
    int c = r - BN;
    const float4* ce = (const float4*)(centers + c * EE);
    const float4* w0 = (const float4*)(fc_w + (size_t)(2 * lane) * EE);
    const float4* w1 = (const float4*)(fc_w + (size_t)(2 * lane + 1) * EE);
    float s0 = 0.f, s1 = 0.f;
#pragma unroll 8
    for (int e = 0; e < 64; ++e) {
      float4 a = ce[e];
      float4 x = w0[e];
      float4 y = w1[e];
      s0 += a.x * x.x + a.y * x.y + a.z * x.z + a.w * x.w;
      s1 += a.x * y.x + a.y * y.y + a.z * y.z + a.w * y.w;
    }
    float2 bb = ((const float2*)fc_b)[lane];
    v.x = s0 + bb.x;
    v.y = s1 + bb.y;
  }
  float ss = v.x * v.x + v.y * v.y;
#pragma unroll
  for (int m = 1; m < 64; m <<= 1) ss += __shfl_xor(ss, m);
  float inv = 1.0f / fmaxf(sqrtf(ss), 1e-8f);
  __hip_bfloat162 h2;
  h2.x = __float2bfloat16(v.x * inv);
  h2.y = __float2bfloat16(v.y * inv);
  ((__hip_bfloat162*)(rn + (size_t)r * HH))[lane] = h2;
  // sum of squares of the rounded values (matches what the MFMA diag computes)
  float xr = __bfloat162float(h2.x);
  float yr = __bfloat162float(h2.y);
  float s2 = xr * xr + yr * yr;
#pragma unroll
  for (int m = 1; m < 64; m <<= 1) s2 += __shfl_xor(s2, m);
  if (lane == 0) {
    labp[r] = (r < BN) ? labels[r] : (r < MM ? r - BN : -1);
    ssq[r] = s2;
  }
}

// ---- main kernel: tot_i = sum_j e_ij (incl diag + pad consts, removed later),
// pos_i = sum over label matches. e_ij = exp2((cos_ij - 1)*K2).
// Distance-2 copy-free register pipeline over j-tiles.
__global__ __launch_bounds__(64)
void main_kernel(const __hip_bfloat16* __restrict__ rn,
                 const int* __restrict__ labp,
                 float* __restrict__ tot,
                 float* __restrict__ pos) {
  const int lane = threadIdx.x;
  const int q = lane >> 4, col = lane & 15;
  const int ibase = blockIdx.x * 64;   // 64 i-rows per wave
  const short* rns = (const short*)rn;

  // A fragments: lane holds A[m=col][k = kk*32 + q*8 + 0..7]
  short8 afrag[4][4];
#pragma unroll
  for (int it = 0; it < 4; ++it) {
    const short8* p = (const short8*)(rns + (size_t)(ibase + it * 16 + col) * HH + q * 8);
    afrag[it][0] = p[0];
    afrag[it][1] = p[4];
    afrag[it][2] = p[8];
    afrag[it][3] = p[12];
  }
  int labi[4][4];
#pragma unroll
  for (int it = 0; it < 4; ++it)
#pragma unroll
    for (int r = 0; r < 4; ++r)
      labi[it][r] = labp[ibase + it * 16 + q * 4 + r];

  float stot[4][4] = {};
  float spos[4][4] = {};

  short8 A0, A1, A2, A3, B0, B1, B2, B3;
  int Al, Bl;

#define LOADSET(R0, R1, R2, R3, RL, TT)                                          \
  {                                                                              \
    const short8* _p = (const short8*)(rns + (size_t)((TT) * 16 + col) * HH + q * 8); \
    R0 = _p[0]; R1 = _p[4]; R2 = _p[8]; R3 = _p[12];                             \
    RL = labp[(TT) * 16 + col];                                                  \
  }

#define COMPUTE(R0, R1, R2, R3, RL)                                              \
  {                                                                              \
    _Pragma("unroll")                                                            \
    for (int it = 0; it < 4; ++it) {                                             \
      floatx4 acc = {0.f, 0.f, 0.f, 0.f};                                        \
      acc = __builtin_amdgcn_mfma_f32_16x16x32_bf16(afrag[it][0], R0, acc, 0, 0, 0); \
      acc = __builtin_amdgcn_mfma_f32_16x16x32_bf16(afrag[it][1], R1, acc, 0, 0, 0); \
      acc = __builtin_amdgcn_mfma_f32_16x16x32_bf16(afrag[it][2], R2, acc, 0, 0, 0); \
      acc = __builtin_amdgcn_mfma_f32_16x16x32_bf16(afrag[it][3], R3, acc, 0, 0, 0); \
      _Pragma("unroll")                                                          \
      for (int r = 0; r < 4; ++r) {                                              \
        float e = __builtin_amdgcn_exp2f(__builtin_fmaf(acc[r], K2, -K2));       \
        stot[it][r] += e;                                                        \
        spos[it][r] += (RL == labi[it][r]) ? e : 0.f;                            \
      }                                                                          \
    }                                                                            \
  }

  int t = blockIdx.y;
  LOADSET(A0, A1, A2, A3, Al, t);
  {
    int tb = t + JCH; if (tb > NTILE - 1) tb = NTILE - 1;
    LOADSET(B0, B1, B2, B3, Bl, tb);
  }
  for (;;) {                       // all branches wave-uniform (depend on blockIdx.y)
    COMPUTE(A0, A1, A2, A3, Al);   // tile t
    if (t + JCH >= NTILE) break;
    {
      int tn = t + 2 * JCH; if (tn > NTILE - 1) tn = NTILE - 1;
      LOADSET(A0, A1, A2, A3, Al, tn);     // prefetch ~1 compute-phase ahead
    }
    COMPUTE(B0, B1, B2, B3, Bl);   // tile t+JCH
    t += 2 * JCH;
    if (t >= NTILE) break;
    {
      int tn = t + JCH; if (tn > NTILE - 1) tn = NTILE - 1;
      LOADSET(B0, B1, B2, B3, Bl, tn);
    }
  }
#undef LOADSET
#undef COMPUTE

  // reduce across the 16 column-lanes (xor over low 4 lane bits)
#pragma unroll
  for (int it = 0; it < 4; ++it)
#pragma unroll
    for (int r = 0; r < 4; ++r) {
      float tt = stot[it][r], pp = spos[it][r];
#pragma unroll
      for (int m = 1; m <= 8; m <<= 1) {
        tt += __shfl_xor(tt, m);
        pp += __shfl_xor(pp, m);
      }
      if (col == 0) {
        int i = ibase + it * 16 + q * 4 + r;
        atomicAdd(&tot[i], tt);
        atomicAdd(&pos[i], pp);
      }
    }
}

// ---- loss kernel: lv = -log((p/t)/(hist+eps)+eps); loss = sum(lv>0.3 ? lv : 0)/count
__global__ __launch_bounds__(1024)
void loss_kernel(const float* __restrict__ tot,
                 const float* __restrict__ pos,
                 const float* __restrict__ ssq,
                 const int* __restrict__ labels,
                 float* __restrict__ out) {
  __shared__ float hist[7];
  __shared__ float s1[16], s2[16];
  const int tid = threadIdx.x;
  const int lane = tid & 63, wv = tid >> 6;
  if (tid < 7) hist[tid] = 0.f;
  __syncthreads();
  // histogram via per-thread compare-add (no atomic storm)
  float c0 = 0, c1 = 0, c2 = 0, c3 = 0, c4 = 0, c5 = 0, c6 = 0;
  for (int i = tid; i < BN; i += 1024) {
    int lab = labels[i];
    c0 += (lab == 0); c1 += (lab == 1); c2 += (lab == 2); c3 += (lab == 3);
    c4 += (lab == 4); c5 += (lab == 5); c6 += (lab == 6);
  }
  float cc[7] = {c0, c1, c2, c3, c4, c5, c6};
#pragma unroll
  for (int k = 0; k < 7; ++k) {
    float v = cc[k];
#pragma unroll
    for (int m = 1; m < 64; m <<= 1) v += __shfl_xor(v, m);
    if (lane == 0) atomicAdd(&hist[k], v);
  }
  __syncthreads();
  float h[7];
#pragma unroll
  for (int k = 0; k < 7; ++k) h[k] = hist[k];
  const float padc = 9.0f * exp2f(-K2);   // pad-row contribution (exact-zero rows)
  float lsum = 0.f, msum = 0.f;
  for (int i = tid; i < BN; i += 1024) {
    int lab = labels[i];
    float ch = h[0];
#pragma unroll
    for (int k = 1; k < 7; ++k) ch = (lab == k) ? h[k] : ch;
    float eii = exp2f((ssq[i] - 1.f) * K2);   // diagonal term, removed here
    float t = tot[i] - padc - eii;
    float p = pos[i] - eii;
    float pr = (p / t) / (ch + 1e-8f);
    float lv = -logf(pr + 1e-8f);
    if (lv > 0.3f) { lsum += lv; msum += 1.f; }
  }
#pragma unroll
  for (int m = 1; m < 64; m <<= 1) {
    lsum += __shfl_xor(lsum, m);
    msum += __shfl_xor(msum, m);
  }
  if (lane == 0) { s1[wv] = lsum; s2[wv] = msum; }
  __syncthreads();
  if (tid == 0) {
    float L = 0.f, M = 0.f;
    for (int w = 0; w < 16; ++w) { L += s1[w]; M += s2[w]; }
    out[0] = L / (M + 1e-8f);
  }
}

extern "C" void kernel_launch(void* const* d_in, const int* in_sizes, int n_in,
                              void* d_out, int out_size, void* d_ws, size_t ws_size,
                              hipStream_t stream) {
  const float* reps    = (const float*)d_in[0];  // [8192,128]
  const int*   labels  = (const int*)d_in[1];    // [8192]
  const float* centers = (const float*)d_in[2];  // [7,256]
  const float* fc_w    = (const float*)d_in[3];  // [128,256]
  const float* fc_b    = (const float*)d_in[4];  // [128]
  float* out = (float*)d_out;

  char* ws = (char*)d_ws;
  int* labp  = (int*)ws;                                  // 8208*4
  float* ssq = (float*)(ws + 36864);                      // 8208*4
  __hip_bfloat16* rn = (__hip_bfloat16*)(ws + 73728);     // 8208*128*2 = 2101248
  float* tot = (float*)(ws + 73728 + 2101248);            // 8192*4
  float* pos = tot + BN;                                  // 8192*4

  hipMemsetAsync(tot, 0, 2 * BN * sizeof(float), stream);
  norm_kernel<<<MP / 4, 256, 0, stream>>>(reps, centers, fc_w, fc_b, labels, rn, labp, ssq);
  main_kernel<<<dim3(BN / 64, JCH), 64, 0, stream>>>(rn, labp, tot, pos);
  loss_kernel<<<1, 1024, 0, stream>>>(tot, pos, ssq, labels, out);
}

// Round 4
// 145.211 us; speedup vs baseline: 1.1228x; 1.0080x over previous
//
#include <hip/hip_runtime.h>
#include <hip/hip_bf16.h>

#define BN 8192      // batch rows
#define MM 8199      // real rows (BN + 7 centers)
#define MP 8208      // padded to multiple of 16
#define HH 128       // feature dim
#define EE 256       // center embedding dim
#define NTILE 513    // MP / 16 j-tiles
#define JCH 32       // j-chunks (grid.y)
#define K2 10.30496147f   // (0.5/0.07) * log2(e)

typedef __attribute__((ext_vector_type(8))) short short8;   // 8 bf16 = 4 VGPRs
typedef __attribute__((ext_vector_type(4))) float floatx4;

// ---- norm kernel: rn[r] = bf16(row / max(||row||,1e-8)); rows >= BN are projected
// centers computed inline; pad rows [MM,MP) exact zeros. Also stores
// ssq[r] = sum of squares of the bf16-rounded normalized row (for diag removal).
__global__ __launch_bounds__(256)
void norm_kernel(const float* __restrict__ reps,
                 const float* __restrict__ centers,
                 const float* __restrict__ fc_w,
                 const float* __restrict__ fc_b,
                 const int* __restrict__ labels,
                 __hip_bfloat16* __restrict__ rn,
                 int* __restrict__ labp,
                 float* __restrict__ ssq) {
  const int lane = threadIdx.x & 63;
  const int r = blockIdx.x * 4 + (threadIdx.x >> 6);
  float2 v = make_float2(0.f, 0.f);
  if (r < BN) {
    v = ((const float2*)(reps + (size_t)r * HH))[lane];
  } else if (r < MM) {
    int c = r - BN;
    const float4* ce = (const float4*)(centers + c * EE);
    const float4* w0 = (const float4*)(fc_w + (size_t)(2 * lane) * EE);
    const float4* w1 = (const float4*)(fc_w + (size_t)(2 * lane + 1) * EE);
    float s0 = 0.f, s1 = 0.f;
#pragma unroll 8
    for (int e = 0; e < 64; ++e) {
      float4 a = ce[e];
      float4 x = w0[e];
      float4 y = w1[e];
      s0 += a.x * x.x + a.y * x.y + a.z * x.z + a.w * x.w;
      s1 += a.x * y.x + a.y * y.y + a.z * y.z + a.w * y.w;
    }
    float2 bb = ((const float2*)fc_b)[lane];
    v.x = s0 + bb.x;
    v.y = s1 + bb.y;
  }
  float ss = v.x * v.x + v.y * v.y;
#pragma unroll
  for (int m = 1; m < 64; m <<= 1) ss += __shfl_xor(ss, m);
  float inv = 1.0f / fmaxf(sqrtf(ss), 1e-8f);
  __hip_bfloat162 h2;
  h2.x = __float2bfloat16(v.x * inv);
  h2.y = __float2bfloat16(v.y * inv);
  ((__hip_bfloat162*)(rn + (size_t)r * HH))[lane] = h2;
  // sum of squares of the rounded values (matches what the MFMA diag computes)
  float xr = __bfloat162float(h2.x);
  float yr = __bfloat162float(h2.y);
  float s2 = xr * xr + yr * yr;
#pragma unroll
  for (int m = 1; m < 64; m <<= 1) s2 += __shfl_xor(s2, m);
  if (lane == 0) {
    labp[r] = (r < BN) ? labels[r] : (r < MM ? r - BN : -1);
    ssq[r] = s2;
  }
}

// ---- main kernel: tot_i = sum_j e_ij (incl diag + pad consts, removed later),
// pos_i = sum over label matches. e_ij = exp2((cos_ij - 1)*K2).
// Distance-2 copy-free register pipeline over j-tiles.
// __launch_bounds__(64, 2): 256-VGPR budget so afrag (64 regs) + pipeline (34) +
// stot/spos (32) stay RESIDENT — at (64) default the compiler allocated 88 VGPRs
// and re-loaded afrag from global inside every compute phase (R3: 3000 cyc/tile).
__global__ __launch_bounds__(64, 2)
void main_kernel(const __hip_bfloat16* __restrict__ rn,
                 const int* __restrict__ labp,
                 float* __restrict__ tot,
                 float* __restrict__ pos) {
  const int lane = threadIdx.x;
  const int q = lane >> 4, col = lane & 15;
  const int ibase = blockIdx.x * 64;   // 64 i-rows per wave
  const short* rns = (const short*)rn;

  // A fragments: lane holds A[m=col][k = kk*32 + q*8 + 0..7]
  short8 afrag[4][4];
#pragma unroll
  for (int it = 0; it < 4; ++it) {
    const short8* p = (const short8*)(rns + (size_t)(ibase + it * 16 + col) * HH + q * 8);
    afrag[it][0] = p[0];
    afrag[it][1] = p[4];
    afrag[it][2] = p[8];
    afrag[it][3] = p[12];
  }
  int labi[4][4];
#pragma unroll
  for (int it = 0; it < 4; ++it)
#pragma unroll
    for (int r = 0; r < 4; ++r)
      labi[it][r] = labp[ibase + it * 16 + q * 4 + r];

  float stot[4][4] = {};
  float spos[4][4] = {};

  short8 A0, A1, A2, A3, B0, B1, B2, B3;
  int Al, Bl;

#define LOADSET(R0, R1, R2, R3, RL, TT)                                          \
  {                                                                              \
    const short8* _p = (const short8*)(rns + (size_t)((TT) * 16 + col) * HH + q * 8); \
    R0 = _p[0]; R1 = _p[4]; R2 = _p[8]; R3 = _p[12];                             \
    RL = labp[(TT) * 16 + col];                                                  \
  }

#define COMPUTE(R0, R1, R2, R3, RL)                                              \
  {                                                                              \
    _Pragma("unroll")                                                            \
    for (int it = 0; it < 4; ++it) {                                             \
      floatx4 acc = {0.f, 0.f, 0.f, 0.f};                                        \
      acc = __builtin_amdgcn_mfma_f32_16x16x32_bf16(afrag[it][0], R0, acc, 0, 0, 0); \
      acc = __builtin_amdgcn_mfma_f32_16x16x32_bf16(afrag[it][1], R1, acc, 0, 0, 0); \
      acc = __builtin_amdgcn_mfma_f32_16x16x32_bf16(afrag[it][2], R2, acc, 0, 0, 0); \
      acc = __builtin_amdgcn_mfma_f32_16x16x32_bf16(afrag[it][3], R3, acc, 0, 0, 0); \
      _Pragma("unroll")                                                          \
      for (int r = 0; r < 4; ++r) {                                              \
        float e = __builtin_amdgcn_exp2f(__builtin_fmaf(acc[r], K2, -K2));       \
        stot[it][r] += e;                                                        \
        spos[it][r] += (RL == labi[it][r]) ? e : 0.f;                            \
      }                                                                          \
    }                                                                            \
  }

  int t = blockIdx.y;
  LOADSET(A0, A1, A2, A3, Al, t);
  {
    int tb = t + JCH; if (tb > NTILE - 1) tb = NTILE - 1;
    LOADSET(B0, B1, B2, B3, Bl, tb);
  }
  for (;;) {                       // all branches wave-uniform (depend on blockIdx.y)
    COMPUTE(A0, A1, A2, A3, Al);   // tile t
    if (t + JCH >= NTILE) break;
    {
      int tn = t + 2 * JCH; if (tn > NTILE - 1) tn = NTILE - 1;
      LOADSET(A0, A1, A2, A3, Al, tn);     // prefetch ~1 compute-phase ahead
    }
    COMPUTE(B0, B1, B2, B3, Bl);   // tile t+JCH
    t += 2 * JCH;
    if (t >= NTILE) break;
    {
      int tn = t + JCH; if (tn > NTILE - 1) tn = NTILE - 1;
      LOADSET(B0, B1, B2, B3, Bl, tn);
    }
  }
#undef LOADSET
#undef COMPUTE

  // reduce across the 16 column-lanes (xor over low 4 lane bits)
#pragma unroll
  for (int it = 0; it < 4; ++it)
#pragma unroll
    for (int r = 0; r < 4; ++r) {
      float tt = stot[it][r], pp = spos[it][r];
#pragma unroll
      for (int m = 1; m <= 8; m <<= 1) {
        tt += __shfl_xor(tt, m);
        pp += __shfl_xor(pp, m);
      }
      if (col == 0) {
        int i = ibase + it * 16 + q * 4 + r;
        atomicAdd(&tot[i], tt);
        atomicAdd(&pos[i], pp);
      }
    }
}

// ---- loss kernel: lv = -log((p/t)/(hist+eps)+eps); loss = sum(lv>0.3 ? lv : 0)/count
__global__ __launch_bounds__(1024)
void loss_kernel(const float* __restrict__ tot,
                 const float* __restrict__ pos,
                 const float* __restrict__ ssq,
                 const int* __restrict__ labels,
                 float* __restrict__ out) {
  __shared__ float hist[7];
  __shared__ float s1[16], s2[16];
  const int tid = threadIdx.x;
  const int lane = tid & 63, wv = tid >> 6;
  if (tid < 7) hist[tid] = 0.f;
  __syncthreads();
  // histogram via per-thread compare-add (no atomic storm)
  float c0 = 0, c1 = 0, c2 = 0, c3 = 0, c4 = 0, c5 = 0, c6 = 0;
  for (int i = tid; i < BN; i += 1024) {
    int lab = labels[i];
    c0 += (lab == 0); c1 += (lab == 1); c2 += (lab == 2); c3 += (lab == 3);
    c4 += (lab == 4); c5 += (lab == 5); c6 += (lab == 6);
  }
  float cc[7] = {c0, c1, c2, c3, c4, c5, c6};
#pragma unroll
  for (int k = 0; k < 7; ++k) {
    float v = cc[k];
#pragma unroll
    for (int m = 1; m < 64; m <<= 1) v += __shfl_xor(v, m);
    if (lane == 0) atomicAdd(&hist[k], v);
  }
  __syncthreads();
  float h[7];
#pragma unroll
  for (int k = 0; k < 7; ++k) h[k] = hist[k];
  const float padc = 9.0f * exp2f(-K2);   // pad-row contribution (exact-zero rows)
  float lsum = 0.f, msum = 0.f;
  for (int i = tid; i < BN; i += 1024) {
    int lab = labels[i];
    float ch = h[0];
#pragma unroll
    for (int k = 1; k < 7; ++k) ch = (lab == k) ? h[k] : ch;
    float eii = exp2f((ssq[i] - 1.f) * K2);   // diagonal term, removed here
    float t = tot[i] - padc - eii;
    float p = pos[i] - eii;
    float pr = (p / t) / (ch + 1e-8f);
    float lv = -logf(pr + 1e-8f);
    if (lv > 0.3f) { lsum += lv; msum += 1.f; }
  }
#pragma unroll
  for (int m = 1; m < 64; m <<= 1) {
    lsum += __shfl_xor(lsum, m);
    msum += __shfl_xor(msum, m);
  }
  if (lane == 0) { s1[wv] = lsum; s2[wv] = msum; }
  __syncthreads();
  if (tid == 0) {
    float L = 0.f, M = 0.f;
    for (int w = 0; w < 16; ++w) { L += s1[w]; M += s2[w]; }
    out[0] = L / (M + 1e-8f);
  }
}

extern "C" void kernel_launch(void* const* d_in, const int* in_sizes, int n_in,
                              void* d_out, int out_size, void* d_ws, size_t ws_size,
                              hipStream_t stream) {
  const float* reps    = (const float*)d_in[0];  // [8192,128]
  const int*   labels  = (const int*)d_in[1];    // [8192]
  const float* centers = (const float*)d_in[2];  // [7,256]
  const float* fc_w    = (const float*)d_in[3];  // [128,256]
  const float* fc_b    = (const float*)d_in[4];  // [128]
  float* out = (float*)d_out;

  char* ws = (char*)d_ws;
  int* labp  = (int*)ws;                                  // 8208*4
  float* ssq = (float*)(ws + 36864);                      // 8208*4
  __hip_bfloat16* rn = (__hip_bfloat16*)(ws + 73728);     // 8208*128*2 = 2101248
  float* tot = (float*)(ws + 73728 + 2101248);            // 8192*4
  float* pos = tot + BN;                                  // 8192*4

  hipMemsetAsync(tot, 0, 2 * BN * sizeof(float), stream);
  norm_kernel<<<MP / 4, 256, 0, stream>>>(reps, centers, fc_w, fc_b, labels, rn, labp, ssq);
  main_kernel<<<dim3(BN / 64, JCH), 64, 0, stream>>>(rn, labp, tot, pos);
  loss_kernel<<<1, 1024, 0, stream>>>(tot, pos, ssq, labels, out);
}

// Round 5
// 144.333 us; speedup vs baseline: 1.1296x; 1.0061x over previous
//
#include <hip/hip_runtime.h>
#include <hip/hip_bf16.h>

#define BN 8192      // batch rows
#define MM 8199      // real rows (BN + 7 centers)
#define MP 8208      // padded to multiple of 16
#define HH 128       // feature dim
#define EE 256       // center embedding dim
#define NTILE 513    // MP / 16 j-tiles
#define JCH 32       // j-chunks (grid.y)
#define K2 10.30496147f   // (0.5/0.07) * log2(e)

typedef __attribute__((ext_vector_type(8))) short short8;   // 8 bf16 = 4 VGPRs
typedef __attribute__((ext_vector_type(4))) float floatx4;

// ---- norm kernel: rn[r] = bf16(row / max(||row||,1e-8)); rows >= BN are projected
// centers computed inline; pad rows [MM,MP) exact zeros. Also stores
// ssq[r] = sum of squares of the bf16-rounded normalized row (for diag removal).
__global__ __launch_bounds__(256)
void norm_kernel(const float* __restrict__ reps,
                 const float* __restrict__ centers,
                 const float* __restrict__ fc_w,
                 const float* __restrict__ fc_b,
                 const int* __restrict__ labels,
                 __hip_bfloat16* __restrict__ rn,
                 int* __restrict__ labp,
                 float* __restrict__ ssq) {
  const int lane = threadIdx.x & 63;
  const int r = blockIdx.x * 4 + (threadIdx.x >> 6);
  float2 v = make_float2(0.f, 0.f);
  if (r < BN) {
    v = ((const float2*)(reps + (size_t)r * HH))[lane];
  } else if (r < MM) {
    int c = r - BN;
    const float4* ce = (const float4*)(centers + c * EE);
    const float4* w0 = (const float4*)(fc_w + (size_t)(2 * lane) * EE);
    const float4* w1 = (const float4*)(fc_w + (size_t)(2 * lane + 1) * EE);
    float s0 = 0.f, s1 = 0.f;
#pragma unroll 8
    for (int e = 0; e < 64; ++e) {
      float4 a = ce[e];
      float4 x = w0[e];
      float4 y = w1[e];
      s0 += a.x * x.x + a.y * x.y + a.z * x.z + a.w * x.w;
      s1 += a.x * y.x + a.y * y.y + a.z * y.z + a.w * y.w;
    }
    float2 bb = ((const float2*)fc_b)[lane];
    v.x = s0 + bb.x;
    v.y = s1 + bb.y;
  }
  float ss = v.x * v.x + v.y * v.y;
#pragma unroll
  for (int m = 1; m < 64; m <<= 1) ss += __shfl_xor(ss, m);
  float inv = 1.0f / fmaxf(sqrtf(ss), 1e-8f);
  __hip_bfloat162 h2;
  h2.x = __float2bfloat16(v.x * inv);
  h2.y = __float2bfloat16(v.y * inv);
  ((__hip_bfloat162*)(rn + (size_t)r * HH))[lane] = h2;
  // sum of squares of the rounded values (matches what the MFMA diag computes)
  float xr = __bfloat162float(h2.x);
  float yr = __bfloat162float(h2.y);
  float s2 = xr * xr + yr * yr;
#pragma unroll
  for (int m = 1; m < 64; m <<= 1) s2 += __shfl_xor(s2, m);
  if (lane == 0) {
    labp[r] = (r < BN) ? labels[r] : (r < MM ? r - BN : -1);
    ssq[r] = s2;
  }
}

// ---- main kernel: tot_i = sum_j e_ij (incl diag + pad consts, removed later),
// pos_i = sum over label matches. e_ij = exp2((cos_ij - 1)*K2).
// Distance-2 copy-free register pipeline over j-tiles.
// afrag is PINNED via empty inline asm: without it the register allocator
// rematerializes afrag by re-loading from global inside every compute phase
// (R3/R4: VGPR_Count 88/76, 3000 cyc/tile). The opaque asm def makes
// rematerialization impossible. B-pipeline regs are NOT pinned — an asm read
// would force vmcnt at the pin site and destroy the prefetch distance.
__global__ __launch_bounds__(64, 2)
void main_kernel(const __hip_bfloat16* __restrict__ rn,
                 const int* __restrict__ labp,
                 float* __restrict__ tot,
                 float* __restrict__ pos) {
  const int lane = threadIdx.x;
  const int q = lane >> 4, col = lane & 15;
  const int ibase = blockIdx.x * 64;   // 64 i-rows per wave
  const short* rns = (const short*)rn;

  // A fragments: lane holds A[m=col][k = kk*32 + q*8 + 0..7]
  short8 afrag[4][4];
#pragma unroll
  for (int it = 0; it < 4; ++it) {
    const short8* p = (const short8*)(rns + (size_t)(ibase + it * 16 + col) * HH + q * 8);
    afrag[it][0] = p[0];
    afrag[it][1] = p[4];
    afrag[it][2] = p[8];
    afrag[it][3] = p[12];
  }
  int labi[4][4];
#pragma unroll
  for (int it = 0; it < 4; ++it)
#pragma unroll
    for (int r = 0; r < 4; ++r)
      labi[it][r] = labp[ibase + it * 16 + q * 4 + r];

  // Opaque defs: force afrag + labi to stay resident in registers.
#pragma unroll
  for (int it = 0; it < 4; ++it) {
#pragma unroll
    for (int k = 0; k < 4; ++k)
      asm("" : "+v"(afrag[it][k]));
#pragma unroll
    for (int r = 0; r < 4; ++r)
      asm("" : "+v"(labi[it][r]));
  }

  float stot[4][4] = {};
  float spos[4][4] = {};

  short8 A0, A1, A2, A3, B0, B1, B2, B3;
  int Al, Bl;

#define LOADSET(R0, R1, R2, R3, RL, TT)                                          \
  {                                                                              \
    const short8* _p = (const short8*)(rns + (size_t)((TT) * 16 + col) * HH + q * 8); \
    R0 = _p[0]; R1 = _p[4]; R2 = _p[8]; R3 = _p[12];                             \
    RL = labp[(TT) * 16 + col];                                                  \
  }

#define COMPUTE(R0, R1, R2, R3, RL)                                              \
  {                                                                              \
    _Pragma("unroll")                                                            \
    for (int it = 0; it < 4; ++it) {                                             \
      floatx4 acc = {0.f, 0.f, 0.f, 0.f};                                        \
      acc = __builtin_amdgcn_mfma_f32_16x16x32_bf16(afrag[it][0], R0, acc, 0, 0, 0); \
      acc = __builtin_amdgcn_mfma_f32_16x16x32_bf16(afrag[it][1], R1, acc, 0, 0, 0); \
      acc = __builtin_amdgcn_mfma_f32_16x16x32_bf16(afrag[it][2], R2, acc, 0, 0, 0); \
      acc = __builtin_amdgcn_mfma_f32_16x16x32_bf16(afrag[it][3], R3, acc, 0, 0, 0); \
      _Pragma("unroll")                                                          \
      for (int r = 0; r < 4; ++r) {                                              \
        float e = __builtin_amdgcn_exp2f(__builtin_fmaf(acc[r], K2, -K2));       \
        stot[it][r] += e;                                                        \
        spos[it][r] += (RL == labi[it][r]) ? e : 0.f;                            \
      }                                                                          \
    }                                                                            \
  }

  int t = blockIdx.y;
  LOADSET(A0, A1, A2, A3, Al, t);
  {
    int tb = t + JCH; if (tb > NTILE - 1) tb = NTILE - 1;
    LOADSET(B0, B1, B2, B3, Bl, tb);
  }
  for (;;) {                       // all branches wave-uniform (depend on blockIdx.y)
    COMPUTE(A0, A1, A2, A3, Al);   // tile t
    if (t + JCH >= NTILE) break;
    {
      int tn = t + 2 * JCH; if (tn > NTILE - 1) tn = NTILE - 1;
      LOADSET(A0, A1, A2, A3, Al, tn);     // prefetch ~1 compute-phase ahead
    }
    COMPUTE(B0, B1, B2, B3, Bl);   // tile t+JCH
    t += 2 * JCH;
    if (t >= NTILE) break;
    {
      int tn = t + JCH; if (tn > NTILE - 1) tn = NTILE - 1;
      LOADSET(B0, B1, B2, B3, Bl, tn);
    }
  }
#undef LOADSET
#undef COMPUTE

  // reduce across the 16 column-lanes (xor over low 4 lane bits)
#pragma unroll
  for (int it = 0; it < 4; ++it)
#pragma unroll
    for (int r = 0; r < 4; ++r) {
      float tt = stot[it][r], pp = spos[it][r];
#pragma unroll
      for (int m = 1; m <= 8; m <<= 1) {
        tt += __shfl_xor(tt, m);
        pp += __shfl_xor(pp, m);
      }
      if (col == 0) {
        int i = ibase + it * 16 + q * 4 + r;
        atomicAdd(&tot[i], tt);
        atomicAdd(&pos[i], pp);
      }
    }
}

// ---- loss kernel: lv = -log((p/t)/(hist+eps)+eps); loss = sum(lv>0.3 ? lv : 0)/count
__global__ __launch_bounds__(1024)
void loss_kernel(const float* __restrict__ tot,
                 const float* __restrict__ pos,
                 const float* __restrict__ ssq,
                 const int* __restrict__ labels,
                 float* __restrict__ out) {
  __shared__ float hist[7];
  __shared__ float s1[16], s2[16];
  const int tid = threadIdx.x;
  const int lane = tid & 63, wv = tid >> 6;
  if (tid < 7) hist[tid] = 0.f;
  __syncthreads();
  // histogram via per-thread compare-add (no atomic storm)
  float c0 = 0, c1 = 0, c2 = 0, c3 = 0, c4 = 0, c5 = 0, c6 = 0;
  for (int i = tid; i < BN; i += 1024) {
    int lab = labels[i];
    c0 += (lab == 0); c1 += (lab == 1); c2 += (lab == 2); c3 += (lab == 3);
    c4 += (lab == 4); c5 += (lab == 5); c6 += (lab == 6);
  }
  float cc[7] = {c0, c1, c2, c3, c4, c5, c6};
#pragma unroll
  for (int k = 0; k < 7; ++k) {
    float v = cc[k];
#pragma unroll
    for (int m = 1; m < 64; m <<= 1) v += __shfl_xor(v, m);
    if (lane == 0) atomicAdd(&hist[k], v);
  }
  __syncthreads();
  float h[7];
#pragma unroll
  for (int k = 0; k < 7; ++k) h[k] = hist[k];
  const float padc = 9.0f * exp2f(-K2);   // pad-row contribution (exact-zero rows)
  float lsum = 0.f, msum = 0.f;
  for (int i = tid; i < BN; i += 1024) {
    int lab = labels[i];
    float ch = h[0];
#pragma unroll
    for (int k = 1; k < 7; ++k) ch = (lab == k) ? h[k] : ch;
    float eii = exp2f((ssq[i] - 1.f) * K2);   // diagonal term, removed here
    float t = tot[i] - padc - eii;
    float p = pos[i] - eii;
    float pr = (p / t) / (ch + 1e-8f);
    float lv = -logf(pr + 1e-8f);
    if (lv > 0.3f) { lsum += lv; msum += 1.f; }
  }
#pragma unroll
  for (int m = 1; m < 64; m <<= 1) {
    lsum += __shfl_xor(lsum, m);
    msum += __shfl_xor(msum, m);
  }
  if (lane == 0) { s1[wv] = lsum; s2[wv] = msum; }
  __syncthreads();
  if (tid == 0) {
    float L = 0.f, M = 0.f;
    for (int w = 0; w < 16; ++w) { L += s1[w]; M += s2[w]; }
    out[0] = L / (M + 1e-8f);
  }
}

extern "C" void kernel_launch(void* const* d_in, const int* in_sizes, int n_in,
                              void* d_out, int out_size, void* d_ws, size_t ws_size,
                              hipStream_t stream) {
  const float* reps    = (const float*)d_in[0];  // [8192,128]
  const int*   labels  = (const int*)d_in[1];    // [8192]
  const float* centers = (const float*)d_in[2];  // [7,256]
  const float* fc_w    = (const float*)d_in[3];  // [128,256]
  const float* fc_b    = (const float*)d_in[4];  // [128]
  float* out = (float*)d_out;

  char* ws = (char*)d_ws;
  int* labp  = (int*)ws;                                  // 8208*4
  float* ssq = (float*)(ws + 36864);                      // 8208*4
  __hip_bfloat16* rn = (__hip_bfloat16*)(ws + 73728);     // 8208*128*2 = 2101248
  float* tot = (float*)(ws + 73728 + 2101248);            // 8192*4
  float* pos = tot + BN;                                  // 8192*4

  hipMemsetAsync(tot, 0, 2 * BN * sizeof(float), stream);
  norm_kernel<<<MP / 4, 256, 0, stream>>>(reps, centers, fc_w, fc_b, labels, rn, labp, ssq);
  main_kernel<<<dim3(BN / 64, JCH), 64, 0, stream>>>(rn, labp, tot, pos);
  loss_kernel<<<1, 1024, 0, stream>>>(tot, pos, ssq, labels, out);
}